// Round 13
// baseline (698.379 us; speedup 1.0000x reference)
//
#include <hip/hip_runtime.h>
#include <hip/hip_cooperative_groups.h>

namespace cg = cooperative_groups;

#define N_ATOMS 10000
#define N_EDGES 160000
#define N_STRUCT 8
#define D_PAD 48
#define PI_F 3.14159265358979323846f
#define NBLK 512
#define NTHR 256
#define TOT (NBLK * NTHR)      // 131072 threads
#define NWAVES (TOT / 64)      // 2048 waves

typedef __attribute__((ext_vector_type(8))) short bf16x8;
typedef __attribute__((ext_vector_type(4))) float f32x4;
typedef unsigned short ushort;
typedef unsigned int uint;

// L fragments: [atom][n][kt][lane][j] bf16 (A-operand; r12-verified layout)
// H fragments: [atom][kt][lane][j]   bf16 (B-operand; congruent k-map)
#define L_WORDS ((size_t)N_ATOMS * 4 * 2 * 64 * 8)
#define H_WORDS ((size_t)N_ATOMS * 2 * 64 * 8)
#define N_SLOTS (N_ATOMS * D_PAD)

__device__ __forceinline__ ushort bf16_rn(float x) {
    uint u = __float_as_uint(x);
    return (ushort)((u + 0x7FFFu + ((u >> 16) & 1u)) >> 16);
}

// ---- per-layer H build: pad slots (snd<0) contribute exact 0 ----
__device__ __forceinline__ void phase_build_H(int tid, const int* __restrict__ snd,
                                              const float* __restrict__ h,
                                              ushort* __restrict__ Hb) {
    for (int g = tid; g < N_ATOMS * 2 * 64; g += TOT) {
        const int lane = g & 63, kt = (g >> 6) & 1, a = g >> 7;
        const int c = lane & 15, quad = lane >> 4;
        ushort outv[8];
        #pragma unroll
        for (int j = 0; j < 8; ++j) {
            int q = kt * 32 + quad * 8 + j;
            float x = 0.f;
            if (q < D_PAD) {
                int s = snd[a * D_PAD + q];
                if ((unsigned)s < N_ATOMS) x = h[s * 16 + c];
            }
            outv[j] = bf16_rn(x);
        }
        *(uint4*)(Hb + (size_t)g * 8) = *(uint4*)outv;
    }
}

// ---- wave-autonomous MP contraction for one atom (r12-verified math) ----
__device__ __forceinline__ void phase_mp(int lane, float* strip,
                                         const ushort* __restrict__ Lb,
                                         const ushort* __restrict__ Hb,
                                         const float* __restrict__ W_inv,
                                         const float* __restrict__ cemb,
                                         float* __restrict__ h_out,
                                         const float* __restrict__ w_out,
                                         const float* __restrict__ comp_w,
                                         const int* __restrict__ species,
                                         const int* __restrict__ sids,
                                         float* __restrict__ accum,
                                         int a, int do_energy) {
    const int quad = lane >> 4, c16 = lane & 15;
    const bf16x8* Hf8 = (const bf16x8*)(Hb + ((size_t)a * 2 * 64) * 8);
    bf16x8 Hf0 = Hf8[lane];
    bf16x8 Hf1 = Hf8[64 + lane];

    f32x4 acc[4];
    #pragma unroll
    for (int n = 0; n < 4; ++n) {
        const bf16x8* Lf8 = (const bf16x8*)(Lb + ((((size_t)a * 4 + n) * 2) << 9));
        bf16x8 L0 = Lf8[lane];
        bf16x8 L1 = Lf8[64 + lane];
        f32x4 z = {0.f, 0.f, 0.f, 0.f};
        z = __builtin_amdgcn_mfma_f32_16x16x32_bf16(L0, Hf0, z, 0, 0, 0);
        z = __builtin_amdgcn_mfma_f32_16x16x32_bf16(L1, Hf1, z, 0, 0, 0);
        acc[n] = z;
    }

    // C (col=lane&15, row=quad*4+reg) -> strip[m*64 + n*16 + c]
    #pragma unroll
    for (int n = 0; n < 4; ++n)
        #pragma unroll
        for (int reg = 0; reg < 4; ++reg)
            strip[(quad * 4 + reg) * 64 + n * 16 + c16] = acc[n][reg];

    const float sc_l[4] = {1.0f, 0.57735026918962576f, 0.44721359549995794f,
                           0.37796447300922720f};
    float inv4[4];
    #pragma unroll
    for (int i = 0; i < 4; ++i) {
        const int kt = lane * 4 + i;
        const int le = kt >> 6, c64 = kt & 63;
        const int m0 = le * le, m1 = m0 + 2 * le;
        float s = 0.f;
        for (int mm = m0; mm <= m1; ++mm) {
            float v = strip[mm * 64 + c64];
            s = fmaf(v, v, s);
        }
        inv4[i] = s * sc_l[le];
    }

    if (do_energy) {
        float s = 0.f;
        #pragma unroll
        for (int i = 0; i < 4; ++i) s = fmaf(inv4[i], w_out[lane * 4 + i], s);
        #pragma unroll
        for (int off = 32; off > 0; off >>= 1) s += __shfl_down(s, off);
        if (lane == 0) atomicAdd(&accum[sids[a]], s + comp_w[species[a]]);
    } else {
        float* sinv = strip + 1024;
        *(float4*)&sinv[lane * 4] = make_float4(inv4[0], inv4[1], inv4[2], inv4[3]);
        // matvec: lane=(g,c2) sums k = g*64 + j
        const int c2 = lane & 15, g = lane >> 4;
        float p = 0.f;
        #pragma unroll 8
        for (int j = 0; j < 64; ++j) {
            const int k = g * 64 + j;
            p = fmaf(sinv[k], W_inv[k * 16 + c2], p);
        }
        p += __shfl_xor(p, 16);
        p += __shfl_xor(p, 32);
        if (lane < 16) h_out[a * 16 + lane] = p * cemb[a * 16 + lane];
    }
}

// ---------------- the fused cooperative kernel ----------------

__global__ __launch_bounds__(NTHR) void fused(
    const float* __restrict__ positions, const float* __restrict__ embed,
    const float* __restrict__ W_rad, const float* __restrict__ W_inv1,
    const float* __restrict__ W_inv2, const float* __restrict__ w_out,
    const float* __restrict__ comp_w, const int* __restrict__ senders,
    const int* __restrict__ receivers, const int* __restrict__ species,
    const int* __restrict__ sids, float* __restrict__ out,
    ushort* __restrict__ Lb, ushort* __restrict__ Hb,
    float* __restrict__ h0, float* __restrict__ h1,
    int* __restrict__ cursor, int* __restrict__ snd, float* __restrict__ accum)
{
    cg::grid_group grid = cg::this_grid();
    __shared__ float smem[4][1280];   // per-wave strip: 1024 s_part + 256 s_inv

    const int t = threadIdx.x;
    const int tid = blockIdx.x * NTHR + t;
    const int w = t >> 6, lane = t & 63;
    const int wgid = blockIdx.x * 4 + w;
    float* strip = smem[w];

    // ---- P0: init (snd=-1, cursor, accum, h0=embed[species]) ----
    for (int i = tid; i < N_SLOTS; i += TOT) snd[i] = -1;
    if (tid < N_ATOMS) cursor[tid] = tid * D_PAD;
    if (tid < N_STRUCT) accum[tid] = 0.f;
    for (int i = tid; i < N_ATOMS * 16; i += TOT)
        h0[i] = embed[species[i >> 4] * 16 + (i & 15)];
    grid.sync();

    // ---- P1: scatter + edge geometry -> L fragments (bf16, A-layout) ----
    for (int e = tid; e < N_EDGES; e += TOT) {
        int s = senders[e], a = receivers[e];
        int slot = atomicAdd(&cursor[a], 1);
        float dx = positions[a * 3 + 0] - positions[s * 3 + 0];
        float dy = positions[a * 3 + 1] - positions[s * 3 + 1];
        float dz = positions[a * 3 + 2] - positions[s * 3 + 2];
        float r = sqrtf(dx * dx + dy * dy + dz * dz);
        float rr = fmaxf(r, 1e-6f);
        float inv = 1.0f / rr;
        float x = dx * inv, y = dy * inv, z = dz * inv;
        float x2 = x * x, y2 = y * y, z2 = z * z;
        float she[16];
        she[0]  = 0.28209479f;
        she[1]  = 0.48860251f * y;
        she[2]  = 0.48860251f * z;
        she[3]  = 0.48860251f * x;
        she[4]  = 1.09254843f * x * y;
        she[5]  = 1.09254843f * y * z;
        she[6]  = 0.31539157f * (3.0f * z2 - 1.0f);
        she[7]  = 1.09254843f * x * z;
        she[8]  = 0.54627422f * (x2 - y2);
        she[9]  = 0.59004359f * y * (3.0f * x2 - y2);
        she[10] = 2.89061144f * x * y * z;
        she[11] = 0.45704579f * y * (5.0f * z2 - 1.0f);
        she[12] = 0.37317633f * z * (5.0f * z2 - 3.0f);
        she[13] = 0.45704579f * x * (5.0f * z2 - 1.0f);
        she[14] = 1.44530572f * z * (x2 - y2);
        she[15] = 0.59004359f * x * (x2 - 3.0f * y2);
        float fc = 0.5f * (cosf(PI_F * fminf(r * 0.2f, 1.0f)) + 1.0f);
        const float c0 = 0.6324555320336759f;
        float bfv[8];
        #pragma unroll
        for (int n = 0; n < 8; ++n)
            bfv[n] = c0 * sinf((float)(n + 1) * PI_F * rr * 0.2f) * inv * fc;
        float Re[16];
        #pragma unroll
        for (int l = 0; l < 4; ++l)
            #pragma unroll
            for (int n = 0; n < 4; ++n) {
                float acc2 = 0.0f;
                #pragma unroll
                for (int b = 0; b < 8; ++b)
                    acc2 = fmaf(bfv[b], W_rad[l * 32 + b * 4 + n], acc2);
                Re[l * 4 + n] = acc2;
            }
        const int a0 = slot / D_PAD;              // == a
        const int qi = slot - a0 * D_PAD;
        const int kt = qi >> 5, r5 = qi & 31;
        const int quad = r5 >> 3, j = r5 & 7;
        const int lm[16] = {0, 1, 1, 1, 2, 2, 2, 2, 2, 3, 3, 3, 3, 3, 3, 3};
        #pragma unroll
        for (int n = 0; n < 4; ++n) {
            size_t base = ((((size_t)a0 * 4 + n) * 2 + kt) << 9);
            #pragma unroll
            for (int m = 0; m < 16; ++m)
                Lb[base + (size_t)((quad << 4) + m) * 8 + j] =
                    bf16_rn(she[m] * Re[lm[m] * 4 + n]);
        }
        snd[slot] = s;
    }
    grid.sync();

    // ---- P2: H(h0) ----
    phase_build_H(tid, snd, h0, Hb);
    grid.sync();

    // ---- P3: layer 1 -> h1 ----
    for (int a = wgid; a < N_ATOMS; a += NWAVES)
        phase_mp(lane, strip, Lb, Hb, W_inv1, h0, h1, w_out, comp_w,
                 species, sids, accum, a, 0);
    grid.sync();

    // ---- P4: H(h1) ----
    phase_build_H(tid, snd, h1, Hb);
    grid.sync();

    // ---- P5: layer 2 -> energy ----
    for (int a = wgid; a < N_ATOMS; a += NWAVES)
        phase_mp(lane, strip, Lb, Hb, W_inv2, h0, h1, w_out, comp_w,
                 species, sids, accum, a, 1);
    grid.sync();

    // ---- P6: output ----
    if (blockIdx.x == 0 && t < N_STRUCT) out[t] = accum[t];
}

// ---------------- launch ----------------

extern "C" void kernel_launch(void* const* d_in, const int* in_sizes, int n_in,
                              void* d_out, int out_size, void* d_ws, size_t ws_size,
                              hipStream_t stream) {
    const float* positions = (const float*)d_in[0];
    const float* embed     = (const float*)d_in[1];
    const float* W_rad     = (const float*)d_in[2];
    const float* W_inv1    = (const float*)d_in[3];
    const float* W_inv2    = (const float*)d_in[4];
    const float* w_out     = (const float*)d_in[5];
    const float* comp_w    = (const float*)d_in[6];
    const int* senders    = (const int*)d_in[7];
    const int* receivers  = (const int*)d_in[8];
    const int* species    = (const int*)d_in[9];
    const int* sids       = (const int*)d_in[10];
    float* out = (float*)d_out;

    char* ws = (char*)d_ws;
    size_t off = 0;
    auto alloc = [&](size_t bytes) -> void* {
        void* p = ws + off;
        off = (off + bytes + 255) & ~(size_t)255;
        return p;
    };
    ushort* Lb    = (ushort*)alloc(L_WORDS * 2);              // 81.92 MB
    ushort* Hb    = (ushort*)alloc(H_WORDS * 2);              // 20.48 MB
    float* h0     = (float*)alloc((size_t)N_ATOMS * 16 * 4);
    float* h1     = (float*)alloc((size_t)N_ATOMS * 16 * 4);
    int*   cursor = (int*)alloc((size_t)N_ATOMS * 4);
    int*   snd    = (int*)alloc((size_t)N_SLOTS * 4);
    float* accum  = (float*)alloc(8 * 4);

    void* args[] = {
        (void*)&positions, (void*)&embed, (void*)&W_rad, (void*)&W_inv1,
        (void*)&W_inv2, (void*)&w_out, (void*)&comp_w, (void*)&senders,
        (void*)&receivers, (void*)&species, (void*)&sids, (void*)&out,
        (void*)&Lb, (void*)&Hb, (void*)&h0, (void*)&h1,
        (void*)&cursor, (void*)&snd, (void*)&accum
    };
    hipLaunchCooperativeKernel((const void*)fused, dim3(NBLK), dim3(NTHR),
                               args, 0, stream);
}